// Round 1
// baseline (2840.010 us; speedup 1.0000x reference)
//
#include <hip/hip_runtime.h>
#include <hip/hip_bf16.h>

// FNO2d: B=16, CIN=20, H=W=256, WIDTH=64, M1=M2=16, NLAYERS=4, FC_HID=128, COUT=20
// Round 4: proj_kernel was the top dispatch (480us, VGPR=48 < hreg[64] -> compiler
// rematerialized the h loads inside the hd loop, burning VALU issue + L2 latency).
// Fix: __launch_bounds__(256,4) (VGPR cap 128, occupancy target 4 waves/EU) so
// hreg stays register-resident, + 4-way partial dot chains for ILP.
//
// Per-sample workspace (floats): h 4,194,304 | T/G 524,288 | X2 65,536 | Y2 65,536
// = 4,849,664 floats (19.4 MB); CB=16 -> 310 MB.

#define HW_TOT 65536
#define PI2_256 0.024543692606170259758f  // 2*pi/256

__device__ __forceinline__ float gelu_exact(float v) {
    return 0.5f * v * (1.0f + erff(v * 0.70710678118654752440f));
}
#define F4COMP(v, k) ((k)==0?(v).x:(k)==1?(v).y:(k)==2?(v).z:(v).w)

// ---------------- 1x1 conv (lift)
template<int CI, int CO, int WS>
__global__ void __launch_bounds__(256) conv1x1_kernel(
    const float* __restrict__ in, const float* __restrict__ w,
    const float* __restrict__ bias, float* __restrict__ out)
{
    const int b = blockIdx.y;
    const int p = blockIdx.x * 256 + threadIdx.x;
    const float* inp = in + (size_t)b * CI * HW_TOT + p;
    float acc[CO];
#pragma unroll
    for (int o = 0; o < CO; ++o) acc[o] = bias[o];
    for (int ci = 0; ci < CI; ++ci) {
        float hv = inp[(size_t)ci * HW_TOT];
#pragma unroll
        for (int o = 0; o < CO; ++o)
            acc[o] = fmaf(w[o * WS + ci], hv, acc[o]);
    }
    float* op = out + (size_t)b * CO * HW_TOT + p;
#pragma unroll
    for (int o = 0; o < CO; ++o) op[(size_t)o * HW_TOT] = acc[o];
}

// ---------------- forward DFT over y as GEMM: T[row*32 + 2ky+c] = sum_y h[row,y]*W[y][2ky+c]
// W[y][2ky] = cos(2pi y ky/256), W[y][2ky+1] = -sin(...). Block: 128 rows x 32 j, 256 thr.
// Thread: jg = t&7 (j = 4jg..+3), rg = t>>3 (rows rg+32k, k<4). 16 acc.
// Per 4-y: 4 As b128 (8 distinct addrs, disjoint bank quads via pad 68) + 4 Ws b128
// (8 distinct addrs at banks 4jg) -> conflict-free; 64 FMA.
__global__ void __launch_bounds__(256) dfty_kernel(
    const float* __restrict__ h, float* __restrict__ T)
{
    __shared__ float As[128][68];     // y-chunk of 64, padded
    __shared__ float Ws[256][32];     // twiddle table
    __shared__ float cs2[256], sn2[256];
    const int t = threadIdx.x;
    {
        float a = (float)t * PI2_256;
        cs2[t] = cosf(a); sn2[t] = sinf(a);
    }
    __syncthreads();
    for (int i = t; i < 8192; i += 256) {
        int y = i >> 5, j = i & 31, ky = j >> 1;
        int m = (y * ky) & 255;
        Ws[y][j] = (j & 1) ? -sn2[m] : cs2[m];
    }
    // (Ws writes complete before first loop barrier below)

    const size_t rowbase = (size_t)blockIdx.x * 128;
    const int jg = t & 7, rg = t >> 3;
    float acc[4][4];
#pragma unroll
    for (int k = 0; k < 4; ++k)
#pragma unroll
        for (int q = 0; q < 4; ++q) acc[k][q] = 0.0f;

    for (int yc = 0; yc < 256; yc += 64) {
        __syncthreads();   // protect As from previous iteration's readers
        // stage As[128][64]: 2048 float4; lane-consecutive = y-consecutive (coalesced)
#pragma unroll
        for (int it = 0; it < 8; ++it) {
            int idx = t + 256 * it;
            int rr = idx >> 4, c4 = idx & 15;
            float4 v = *(const float4*)(h + (rowbase + rr) * 256 + yc + c4 * 4);
            *(float4*)&As[rr][c4 * 4] = v;
        }
        __syncthreads();
#pragma unroll 2
        for (int yy = 0; yy < 64; yy += 4) {
            float4 wv[4], av[4];
#pragma unroll
            for (int q = 0; q < 4; ++q) wv[q] = *(const float4*)&Ws[yc + yy + q][jg * 4];
#pragma unroll
            for (int k = 0; k < 4; ++k) av[k] = *(const float4*)&As[rg + 32 * k][yy];
#pragma unroll
            for (int k = 0; k < 4; ++k)
#pragma unroll
                for (int q = 0; q < 4; ++q) {
                    float a = F4COMP(av[k], q);
                    acc[k][0] = fmaf(a, wv[q].x, acc[k][0]);
                    acc[k][1] = fmaf(a, wv[q].y, acc[k][1]);
                    acc[k][2] = fmaf(a, wv[q].z, acc[k][2]);
                    acc[k][3] = fmaf(a, wv[q].w, acc[k][3]);
                }
        }
    }
#pragma unroll
    for (int k = 0; k < 4; ++k) {
        float4 v = make_float4(acc[k][0], acc[k][1], acc[k][2], acc[k][3]);
        *(float4*)&T[(rowbase + rg + 32 * k) * 32 + jg * 4] = v;
    }
}

// ---------------- forward DFT over x: X[bc,kxi,ky] = sum_x T[bc,x,ky] * e^{-2pi i kx x/256}
__global__ void __launch_bounds__(512) dft2_kernel(
    const float2* __restrict__ T2, float2* __restrict__ X2)
{
    __shared__ float cs[256], sn[256];
    const int t = threadIdx.x;
    if (t < 256) {
        float a = (float)t * PI2_256;
        cs[t] = cosf(a); sn[t] = sinf(a);
    }
    __syncthreads();
    const int bc = blockIdx.x;
    const int ky = t & 15, kxi = t >> 4;
    const int kx = (kxi < 16) ? kxi : (224 + kxi);
    const float2* Tp = T2 + (size_t)bc * 4096 + ky;
    float xr = 0.0f, xi = 0.0f;
    int m = 0;
    for (int x = 0; x < 256; ++x) {
        float2 tv = Tp[(size_t)x * 16];
        float c = cs[m], s = sn[m];
        xr = fmaf(tv.x, c, fmaf(tv.y, s, xr));
        xi = fmaf(tv.y, c, fmaf(-tv.x, s, xi));
        m = (m + kx) & 255;
    }
    X2[(size_t)bc * 512 + t] = make_float2(xr, xi);
}

// ---------------- complex mode mixing
__global__ void __launch_bounds__(512) mix_kernel(
    const float2* __restrict__ X2, float2* __restrict__ Y2,
    const float* __restrict__ w1r, const float* __restrict__ w1i,
    const float* __restrict__ w2r, const float* __restrict__ w2i, int layer)
{
    const int bo = blockIdx.x;
    const int b = bo >> 6, o = bo & 63;
    const int t = threadIdx.x;
    const int ky = t & 15, kxi = t >> 4;
    const bool top = (kxi < 16);
    const int kxm = top ? kxi : (kxi - 16);
    const float* wr = top ? w1r : w2r;
    const float* wi = top ? w1i : w2i;
    float yr = 0.0f, yi = 0.0f;
    for (int i = 0; i < 64; ++i) {
        float2 xv = X2[((size_t)(b * 64 + i) * 32 + kxi) * 16 + ky];
        size_t widx = (((size_t)layer * 64 + i) * 64 + o) * 256 + (kxm * 16 + ky);
        float wrv = wr[widx], wiv = wi[widx];
        yr = fmaf(xv.x, wrv, fmaf(-xv.y, wiv, yr));
        yi = fmaf(xv.x, wiv, fmaf(xv.y, wrv, yi));
    }
    Y2[((size_t)(b * 64 + o) * 32 + kxi) * 16 + ky] = make_float2(yr, yi);
}

// ---------------- inverse DFT over x
__global__ void __launch_bounds__(256) idft1_kernel(
    const float2* __restrict__ Y2, float2* __restrict__ G2)
{
    __shared__ float cs[256], sn[256];
    const int t = threadIdx.x;
    {
        float a = (float)t * PI2_256;
        cs[t] = cosf(a); sn[t] = sinf(a);
    }
    __syncthreads();
    const int bo = blockIdx.x >> 4;
    const int xc = blockIdx.x & 15;
    const int ky = t & 15, xo = t >> 4;
    const int x = xc * 16 + xo;
    const float2* Yp = Y2 + (size_t)bo * 512 + ky;
    float gr = 0.0f, gi = 0.0f;
    for (int kxi = 0; kxi < 32; ++kxi) {
        float2 yv = Yp[(size_t)kxi * 16];
        int kx = (kxi < 16) ? kxi : (224 + kxi);
        int m = (kx * x) & 255;
        float c = cs[m], s = sn[m];
        gr = fmaf(yv.x, c, fmaf(-yv.y, s, gr));
        gi = fmaf(yv.x, s, fmaf(yv.y, c, gi));
    }
    G2[((size_t)bo * 256 + x) * 16 + ky] = make_float2(gr, gi);
}

// ---------------- fused pointwise conv + iDFT-y + add + GELU, in place on h.
// Single K=96 GEMM per block (ci-part K=64 from hs/Wt, spectral K=32 from Gt/Pt).
// 1024 thr; thread: og = t&15 (o = 4og..+3), yg = t>>4 (y = 4yg..+3).
// Per K-step: 2 partial-broadcast b128 (4 and 16 distinct addrs) per 16 FMA.
__global__ void __launch_bounds__(1024) pwcomb_kernel(
    float* __restrict__ h, const float2* __restrict__ G2,
    const float* __restrict__ pw_w, const float* __restrict__ pw_b,
    int layer, int do_gelu)
{
    __shared__ float hs[64][256];     // [ci][y] 64 KB
    __shared__ float Wt[64][65];      // [ci][o] transposed, padded (16.6 KB)
    __shared__ float Gt[32][64];      // [j'][o] 8 KB
    __shared__ float Pt[32][256];     // [j'][y] 32 KB
    __shared__ float cs[256], sn[256];
    const int t = threadIdx.x;
    const int b = blockIdx.x >> 8;
    const int x = blockIdx.x & 255;
    if (t < 256) {
        float a = (float)t * PI2_256;
        cs[t] = cosf(a); sn[t] = sinf(a);
    }
    __syncthreads();

    // Wt[ci][o] from pw_w[layer][o][ci]
    const float* wl = pw_w + layer * 4096;
    for (int i = t; i < 4096; i += 1024) { int o = i >> 6, ci = i & 63; Wt[ci][o] = wl[i]; }
    // Gt from G2
    {
        int o = t >> 4, ky = t & 15;
        float2 g = G2[((size_t)(b * 64 + o) * 256 + x) * 16 + ky];
        Gt[2 * ky][o] = g.x;
        Gt[2 * ky + 1][o] = g.y;
    }
    // Pt[j'][y]: j'=2ky -> wk*cos(2pi ky y/256); j'=2ky+1 -> -wk*sin(...)
    const float inv = 1.0f / 65536.0f;
#pragma unroll
    for (int it = 0; it < 8; ++it) {
        int i = t + 1024 * it;
        int jp = i >> 8, y = i & 255, ky = jp >> 1;
        int m = (ky * y) & 255;
        float wk = (ky == 0) ? inv : 2.0f * inv;
        Pt[jp][y] = (jp & 1) ? -wk * sn[m] : wk * cs[m];
    }
    // stage hs (all reads of h precede the barrier; writes after -> in-place safe)
#pragma unroll
    for (int it = 0; it < 4; ++it) {
        int idx = t + 1024 * it;
        int ci = idx >> 6, c4 = idx & 63;
        float4 v = *(const float4*)(h + ((size_t)(b * 64 + ci) * 256 + x) * 256 + c4 * 4);
        *(float4*)&hs[ci][c4 * 4] = v;
    }
    __syncthreads();

    const int og = t & 15, yg = t >> 4;
    const float* bl = pw_b + layer * 64;
    float acc[4][4];   // [yj][oj]
#pragma unroll
    for (int oj = 0; oj < 4; ++oj) {
        float bv = bl[og * 4 + oj];
#pragma unroll
        for (int yj = 0; yj < 4; ++yj) acc[yj][oj] = bv;
    }
    // conv part: K = 64
    for (int ci = 0; ci < 64; ++ci) {
        float4 hv = *(const float4*)&hs[ci][yg * 4];
        float4 wv = *(const float4*)&Wt[ci][og * 4];
#pragma unroll
        for (int yj = 0; yj < 4; ++yj) {
            float a = F4COMP(hv, yj);
            acc[yj][0] = fmaf(a, wv.x, acc[yj][0]);
            acc[yj][1] = fmaf(a, wv.y, acc[yj][1]);
            acc[yj][2] = fmaf(a, wv.z, acc[yj][2]);
            acc[yj][3] = fmaf(a, wv.w, acc[yj][3]);
        }
    }
    // spectral part: K = 32
#pragma unroll 4
    for (int jp = 0; jp < 32; ++jp) {
        float4 pv = *(const float4*)&Pt[jp][yg * 4];
        float4 gv = *(const float4*)&Gt[jp][og * 4];
#pragma unroll
        for (int yj = 0; yj < 4; ++yj) {
            float a = F4COMP(pv, yj);
            acc[yj][0] = fmaf(a, gv.x, acc[yj][0]);
            acc[yj][1] = fmaf(a, gv.y, acc[yj][1]);
            acc[yj][2] = fmaf(a, gv.z, acc[yj][2]);
            acc[yj][3] = fmaf(a, gv.w, acc[yj][3]);
        }
    }
    // epilogue: gelu + store (float4 per o-row)
#pragma unroll
    for (int oj = 0; oj < 4; ++oj) {
        float4 v;
        v.x = acc[0][oj]; v.y = acc[1][oj]; v.z = acc[2][oj]; v.w = acc[3][oj];
        if (do_gelu) {
            v.x = gelu_exact(v.x); v.y = gelu_exact(v.y);
            v.z = gelu_exact(v.z); v.w = gelu_exact(v.w);
        }
        *(float4*)&h[((size_t)(b * 64 + og * 4 + oj) * 256 + x) * 256 + yg * 4] = v;
    }
}

// ---------------- fused projection: out = fc2(gelu(fc1(h))) per pixel.
// Round-4: launch_bounds(256,4) caps VGPR at 128 and sets occupancy target 4 waves/EU
// so hreg[64]+acc[20] (~110 VGPR) stays register-resident (R3 build chose 48 VGPR and
// rematerialized the h loads inside the hd loop -> 65% VALUBusy, 30% useful FMA).
// 4-way partial dot chains give ILP 4 within the serial fc1 reduction.
__global__ void __launch_bounds__(256, 4) proj_kernel(
    const float* __restrict__ h,
    const float* __restrict__ w1, const float* __restrict__ b1,
    const float* __restrict__ w2, const float* __restrict__ b2,
    float* __restrict__ out)
{
    const int b = blockIdx.y;
    const int p = blockIdx.x * 256 + threadIdx.x;
    const float* hp = h + (size_t)b * 64 * HW_TOT + p;
    float hreg[64];
#pragma unroll
    for (int ci = 0; ci < 64; ++ci) hreg[ci] = hp[(size_t)ci * HW_TOT];
    float acc[20];
#pragma unroll
    for (int o = 0; o < 20; ++o) acc[o] = b2[o];
    for (int hd = 0; hd < 128; ++hd) {
        const float* wr = w1 + hd * 64;
        float v0 = 0.0f, v1 = 0.0f, v2 = 0.0f, v3 = 0.0f;
#pragma unroll
        for (int ci = 0; ci < 64; ci += 4) {
            v0 = fmaf(wr[ci],     hreg[ci],     v0);
            v1 = fmaf(wr[ci + 1], hreg[ci + 1], v1);
            v2 = fmaf(wr[ci + 2], hreg[ci + 2], v2);
            v3 = fmaf(wr[ci + 3], hreg[ci + 3], v3);
        }
        float v = gelu_exact(b1[hd] + ((v0 + v1) + (v2 + v3)));
#pragma unroll
        for (int o = 0; o < 20; ++o) acc[o] = fmaf(w2[o * 128 + hd], v, acc[o]);
    }
    float* op = out + (size_t)b * 20 * HW_TOT + p;
#pragma unroll
    for (int o = 0; o < 20; ++o) op[(size_t)o * HW_TOT] = acc[o];
}

extern "C" void kernel_launch(void* const* d_in, const int* in_sizes, int n_in,
                              void* d_out, int out_size, void* d_ws, size_t ws_size,
                              hipStream_t stream)
{
    const float* x     = (const float*)d_in[0];
    const float* w1r   = (const float*)d_in[1];
    const float* w1i   = (const float*)d_in[2];
    const float* w2r   = (const float*)d_in[3];
    const float* w2i   = (const float*)d_in[4];
    const float* pw_w  = (const float*)d_in[5];
    const float* pw_b  = (const float*)d_in[6];
    const float* fc0_w = (const float*)d_in[7];
    const float* fc0_b = (const float*)d_in[8];
    const float* fc1_w = (const float*)d_in[9];
    const float* fc1_b = (const float*)d_in[10];
    const float* fc2_w = (const float*)d_in[11];
    const float* fc2_b = (const float*)d_in[12];
    float* out = (float*)d_out;
    float* ws  = (float*)d_ws;

    const size_t per_sample_floats = 4849664;
    int CB = 16;
    while (CB > 1 && (size_t)CB * per_sample_floats * 4 > ws_size) CB >>= 1;

    float*  h  = ws;
    float*  T  = ws + (size_t)CB * 4194304;
    float2* T2 = (float2*)T;
    float2* X2 = (float2*)(T + (size_t)CB * 524288);
    float2* Y2 = (float2*)(T + (size_t)CB * 524288 + (size_t)CB * 65536);
    float2* G2 = T2;   // reuse

    for (int c0 = 0; c0 < 16; c0 += CB) {
        const float* xc = x + (size_t)c0 * 20 * HW_TOT;
        float* oc = out + (size_t)c0 * 20 * HW_TOT;

        conv1x1_kernel<20, 64, 20>
            <<<dim3(256, CB), 256, 0, stream>>>(xc, fc0_w, fc0_b, h);

        for (int l = 0; l < 4; ++l) {
            dfty_kernel <<<CB * 128, 256, 0, stream>>>(h, T);
            dft2_kernel <<<CB * 64, 512, 0, stream>>>(T2, X2);
            mix_kernel  <<<CB * 64, 512, 0, stream>>>(X2, Y2, w1r, w1i, w2r, w2i, l);
            idft1_kernel<<<CB * 64 * 16, 256, 0, stream>>>(Y2, G2);
            pwcomb_kernel<<<CB * 256, 1024, 0, stream>>>(h, G2, pw_w, pw_b, l, (l < 3) ? 1 : 0);
        }

        proj_kernel<<<dim3(256, CB), 256, 0, stream>>>(h, fc1_w, fc1_b, fc2_w, fc2_b, oc);
    }
}

// Round 2
// 2831.738 us; speedup vs baseline: 1.0029x; 1.0029x over previous
//
#include <hip/hip_runtime.h>
#include <hip/hip_bf16.h>

// FNO2d: B=16, CIN=20, H=W=256, WIDTH=64, M1=M2=16, NLAYERS=4, FC_HID=128, COUT=20
// Round 5: R4's __launch_bounds__(256,4) raised the VGPR budget but the compiler
// STILL chose VGPR=48 and rematerialized the h loads inside the hd loop (remat
// heuristic, not budget, is the blocker; VALUBusy fell to 36%). Fix: launder each
// hreg value through an empty inline asm -- asm outputs cannot be rematerialized,
// so the 64 values must stay register-resident (64 h + 20 acc + temps ~ 110 < 128).
//
// Per-sample workspace (floats): h 4,194,304 | T/G 524,288 | X2 65,536 | Y2 65,536
// = 4,849,664 floats (19.4 MB); CB=16 -> 310 MB.

#define HW_TOT 65536
#define PI2_256 0.024543692606170259758f  // 2*pi/256

__device__ __forceinline__ float gelu_exact(float v) {
    return 0.5f * v * (1.0f + erff(v * 0.70710678118654752440f));
}
#define F4COMP(v, k) ((k)==0?(v).x:(k)==1?(v).y:(k)==2?(v).z:(v).w)

// ---------------- 1x1 conv (lift)
template<int CI, int CO, int WS>
__global__ void __launch_bounds__(256) conv1x1_kernel(
    const float* __restrict__ in, const float* __restrict__ w,
    const float* __restrict__ bias, float* __restrict__ out)
{
    const int b = blockIdx.y;
    const int p = blockIdx.x * 256 + threadIdx.x;
    const float* inp = in + (size_t)b * CI * HW_TOT + p;
    float acc[CO];
#pragma unroll
    for (int o = 0; o < CO; ++o) acc[o] = bias[o];
    for (int ci = 0; ci < CI; ++ci) {
        float hv = inp[(size_t)ci * HW_TOT];
#pragma unroll
        for (int o = 0; o < CO; ++o)
            acc[o] = fmaf(w[o * WS + ci], hv, acc[o]);
    }
    float* op = out + (size_t)b * CO * HW_TOT + p;
#pragma unroll
    for (int o = 0; o < CO; ++o) op[(size_t)o * HW_TOT] = acc[o];
}

// ---------------- forward DFT over y as GEMM: T[row*32 + 2ky+c] = sum_y h[row,y]*W[y][2ky+c]
// W[y][2ky] = cos(2pi y ky/256), W[y][2ky+1] = -sin(...). Block: 128 rows x 32 j, 256 thr.
// Thread: jg = t&7 (j = 4jg..+3), rg = t>>3 (rows rg+32k, k<4). 16 acc.
// Per 4-y: 4 As b128 (8 distinct addrs, disjoint bank quads via pad 68) + 4 Ws b128
// (8 distinct addrs at banks 4jg) -> conflict-free; 64 FMA.
__global__ void __launch_bounds__(256) dfty_kernel(
    const float* __restrict__ h, float* __restrict__ T)
{
    __shared__ float As[128][68];     // y-chunk of 64, padded
    __shared__ float Ws[256][32];     // twiddle table
    __shared__ float cs2[256], sn2[256];
    const int t = threadIdx.x;
    {
        float a = (float)t * PI2_256;
        cs2[t] = cosf(a); sn2[t] = sinf(a);
    }
    __syncthreads();
    for (int i = t; i < 8192; i += 256) {
        int y = i >> 5, j = i & 31, ky = j >> 1;
        int m = (y * ky) & 255;
        Ws[y][j] = (j & 1) ? -sn2[m] : cs2[m];
    }
    // (Ws writes complete before first loop barrier below)

    const size_t rowbase = (size_t)blockIdx.x * 128;
    const int jg = t & 7, rg = t >> 3;
    float acc[4][4];
#pragma unroll
    for (int k = 0; k < 4; ++k)
#pragma unroll
        for (int q = 0; q < 4; ++q) acc[k][q] = 0.0f;

    for (int yc = 0; yc < 256; yc += 64) {
        __syncthreads();   // protect As from previous iteration's readers
        // stage As[128][64]: 2048 float4; lane-consecutive = y-consecutive (coalesced)
#pragma unroll
        for (int it = 0; it < 8; ++it) {
            int idx = t + 256 * it;
            int rr = idx >> 4, c4 = idx & 15;
            float4 v = *(const float4*)(h + (rowbase + rr) * 256 + yc + c4 * 4);
            *(float4*)&As[rr][c4 * 4] = v;
        }
        __syncthreads();
#pragma unroll 2
        for (int yy = 0; yy < 64; yy += 4) {
            float4 wv[4], av[4];
#pragma unroll
            for (int q = 0; q < 4; ++q) wv[q] = *(const float4*)&Ws[yc + yy + q][jg * 4];
#pragma unroll
            for (int k = 0; k < 4; ++k) av[k] = *(const float4*)&As[rg + 32 * k][yy];
#pragma unroll
            for (int k = 0; k < 4; ++k)
#pragma unroll
                for (int q = 0; q < 4; ++q) {
                    float a = F4COMP(av[k], q);
                    acc[k][0] = fmaf(a, wv[q].x, acc[k][0]);
                    acc[k][1] = fmaf(a, wv[q].y, acc[k][1]);
                    acc[k][2] = fmaf(a, wv[q].z, acc[k][2]);
                    acc[k][3] = fmaf(a, wv[q].w, acc[k][3]);
                }
        }
    }
#pragma unroll
    for (int k = 0; k < 4; ++k) {
        float4 v = make_float4(acc[k][0], acc[k][1], acc[k][2], acc[k][3]);
        *(float4*)&T[(rowbase + rg + 32 * k) * 32 + jg * 4] = v;
    }
}

// ---------------- forward DFT over x: X[bc,kxi,ky] = sum_x T[bc,x,ky] * e^{-2pi i kx x/256}
__global__ void __launch_bounds__(512) dft2_kernel(
    const float2* __restrict__ T2, float2* __restrict__ X2)
{
    __shared__ float cs[256], sn[256];
    const int t = threadIdx.x;
    if (t < 256) {
        float a = (float)t * PI2_256;
        cs[t] = cosf(a); sn[t] = sinf(a);
    }
    __syncthreads();
    const int bc = blockIdx.x;
    const int ky = t & 15, kxi = t >> 4;
    const int kx = (kxi < 16) ? kxi : (224 + kxi);
    const float2* Tp = T2 + (size_t)bc * 4096 + ky;
    float xr = 0.0f, xi = 0.0f;
    int m = 0;
    for (int x = 0; x < 256; ++x) {
        float2 tv = Tp[(size_t)x * 16];
        float c = cs[m], s = sn[m];
        xr = fmaf(tv.x, c, fmaf(tv.y, s, xr));
        xi = fmaf(tv.y, c, fmaf(-tv.x, s, xi));
        m = (m + kx) & 255;
    }
    X2[(size_t)bc * 512 + t] = make_float2(xr, xi);
}

// ---------------- complex mode mixing
__global__ void __launch_bounds__(512) mix_kernel(
    const float2* __restrict__ X2, float2* __restrict__ Y2,
    const float* __restrict__ w1r, const float* __restrict__ w1i,
    const float* __restrict__ w2r, const float* __restrict__ w2i, int layer)
{
    const int bo = blockIdx.x;
    const int b = bo >> 6, o = bo & 63;
    const int t = threadIdx.x;
    const int ky = t & 15, kxi = t >> 4;
    const bool top = (kxi < 16);
    const int kxm = top ? kxi : (kxi - 16);
    const float* wr = top ? w1r : w2r;
    const float* wi = top ? w1i : w2i;
    float yr = 0.0f, yi = 0.0f;
    for (int i = 0; i < 64; ++i) {
        float2 xv = X2[((size_t)(b * 64 + i) * 32 + kxi) * 16 + ky];
        size_t widx = (((size_t)layer * 64 + i) * 64 + o) * 256 + (kxm * 16 + ky);
        float wrv = wr[widx], wiv = wi[widx];
        yr = fmaf(xv.x, wrv, fmaf(-xv.y, wiv, yr));
        yi = fmaf(xv.x, wiv, fmaf(xv.y, wrv, yi));
    }
    Y2[((size_t)(b * 64 + o) * 32 + kxi) * 16 + ky] = make_float2(yr, yi);
}

// ---------------- inverse DFT over x
__global__ void __launch_bounds__(256) idft1_kernel(
    const float2* __restrict__ Y2, float2* __restrict__ G2)
{
    __shared__ float cs[256], sn[256];
    const int t = threadIdx.x;
    {
        float a = (float)t * PI2_256;
        cs[t] = cosf(a); sn[t] = sinf(a);
    }
    __syncthreads();
    const int bo = blockIdx.x >> 4;
    const int xc = blockIdx.x & 15;
    const int ky = t & 15, xo = t >> 4;
    const int x = xc * 16 + xo;
    const float2* Yp = Y2 + (size_t)bo * 512 + ky;
    float gr = 0.0f, gi = 0.0f;
    for (int kxi = 0; kxi < 32; ++kxi) {
        float2 yv = Yp[(size_t)kxi * 16];
        int kx = (kxi < 16) ? kxi : (224 + kxi);
        int m = (kx * x) & 255;
        float c = cs[m], s = sn[m];
        gr = fmaf(yv.x, c, fmaf(-yv.y, s, gr));
        gi = fmaf(yv.x, s, fmaf(yv.y, c, gi));
    }
    G2[((size_t)bo * 256 + x) * 16 + ky] = make_float2(gr, gi);
}

// ---------------- fused pointwise conv + iDFT-y + add + GELU, in place on h.
// Single K=96 GEMM per block (ci-part K=64 from hs/Wt, spectral K=32 from Gt/Pt).
// 1024 thr; thread: og = t&15 (o = 4og..+3), yg = t>>4 (y = 4yg..+3).
// Per K-step: 2 partial-broadcast b128 (4 and 16 distinct addrs) per 16 FMA.
__global__ void __launch_bounds__(1024) pwcomb_kernel(
    float* __restrict__ h, const float2* __restrict__ G2,
    const float* __restrict__ pw_w, const float* __restrict__ pw_b,
    int layer, int do_gelu)
{
    __shared__ float hs[64][256];     // [ci][y] 64 KB
    __shared__ float Wt[64][65];      // [ci][o] transposed, padded (16.6 KB)
    __shared__ float Gt[32][64];      // [j'][o] 8 KB
    __shared__ float Pt[32][256];     // [j'][y] 32 KB
    __shared__ float cs[256], sn[256];
    const int t = threadIdx.x;
    const int b = blockIdx.x >> 8;
    const int x = blockIdx.x & 255;
    if (t < 256) {
        float a = (float)t * PI2_256;
        cs[t] = cosf(a); sn[t] = sinf(a);
    }
    __syncthreads();

    // Wt[ci][o] from pw_w[layer][o][ci]
    const float* wl = pw_w + layer * 4096;
    for (int i = t; i < 4096; i += 1024) { int o = i >> 6, ci = i & 63; Wt[ci][o] = wl[i]; }
    // Gt from G2
    {
        int o = t >> 4, ky = t & 15;
        float2 g = G2[((size_t)(b * 64 + o) * 256 + x) * 16 + ky];
        Gt[2 * ky][o] = g.x;
        Gt[2 * ky + 1][o] = g.y;
    }
    // Pt[j'][y]: j'=2ky -> wk*cos(2pi ky y/256); j'=2ky+1 -> -wk*sin(...)
    const float inv = 1.0f / 65536.0f;
#pragma unroll
    for (int it = 0; it < 8; ++it) {
        int i = t + 1024 * it;
        int jp = i >> 8, y = i & 255, ky = jp >> 1;
        int m = (ky * y) & 255;
        float wk = (ky == 0) ? inv : 2.0f * inv;
        Pt[jp][y] = (jp & 1) ? -wk * sn[m] : wk * cs[m];
    }
    // stage hs (all reads of h precede the barrier; writes after -> in-place safe)
#pragma unroll
    for (int it = 0; it < 4; ++it) {
        int idx = t + 1024 * it;
        int ci = idx >> 6, c4 = idx & 63;
        float4 v = *(const float4*)(h + ((size_t)(b * 64 + ci) * 256 + x) * 256 + c4 * 4);
        *(float4*)&hs[ci][c4 * 4] = v;
    }
    __syncthreads();

    const int og = t & 15, yg = t >> 4;
    const float* bl = pw_b + layer * 64;
    float acc[4][4];   // [yj][oj]
#pragma unroll
    for (int oj = 0; oj < 4; ++oj) {
        float bv = bl[og * 4 + oj];
#pragma unroll
        for (int yj = 0; yj < 4; ++yj) acc[yj][oj] = bv;
    }
    // conv part: K = 64
    for (int ci = 0; ci < 64; ++ci) {
        float4 hv = *(const float4*)&hs[ci][yg * 4];
        float4 wv = *(const float4*)&Wt[ci][og * 4];
#pragma unroll
        for (int yj = 0; yj < 4; ++yj) {
            float a = F4COMP(hv, yj);
            acc[yj][0] = fmaf(a, wv.x, acc[yj][0]);
            acc[yj][1] = fmaf(a, wv.y, acc[yj][1]);
            acc[yj][2] = fmaf(a, wv.z, acc[yj][2]);
            acc[yj][3] = fmaf(a, wv.w, acc[yj][3]);
        }
    }
    // spectral part: K = 32
#pragma unroll 4
    for (int jp = 0; jp < 32; ++jp) {
        float4 pv = *(const float4*)&Pt[jp][yg * 4];
        float4 gv = *(const float4*)&Gt[jp][og * 4];
#pragma unroll
        for (int yj = 0; yj < 4; ++yj) {
            float a = F4COMP(pv, yj);
            acc[yj][0] = fmaf(a, gv.x, acc[yj][0]);
            acc[yj][1] = fmaf(a, gv.y, acc[yj][1]);
            acc[yj][2] = fmaf(a, gv.z, acc[yj][2]);
            acc[yj][3] = fmaf(a, gv.w, acc[yj][3]);
        }
    }
    // epilogue: gelu + store (float4 per o-row)
#pragma unroll
    for (int oj = 0; oj < 4; ++oj) {
        float4 v;
        v.x = acc[0][oj]; v.y = acc[1][oj]; v.z = acc[2][oj]; v.w = acc[3][oj];
        if (do_gelu) {
            v.x = gelu_exact(v.x); v.y = gelu_exact(v.y);
            v.z = gelu_exact(v.z); v.w = gelu_exact(v.w);
        }
        *(float4*)&h[((size_t)(b * 64 + og * 4 + oj) * 256 + x) * 256 + yg * 4] = v;
    }
}

// ---------------- fused projection: out = fc2(gelu(fc1(h))) per pixel.
// Round-5: VGPR=48 in both R3 (no bounds) and R4 (bounds 256,4) proves the
// compiler's REMAT heuristic, not the budget, sinks the h loads into the hd loop.
// Launder every hreg value through an empty asm: asm results cannot be
// rematerialized, forcing true register residency (~110 VGPR < 128 cap at 4 w/EU).
// Loop body is then pure FMA vs SGPR-resident w1 rows (wave-uniform -> s_load).
__global__ void __launch_bounds__(256, 4) proj_kernel(
    const float* __restrict__ h,
    const float* __restrict__ w1, const float* __restrict__ b1,
    const float* __restrict__ w2, const float* __restrict__ b2,
    float* __restrict__ out)
{
    const int b = blockIdx.y;
    const int p = blockIdx.x * 256 + threadIdx.x;
    const float* hp = h + (size_t)b * 64 * HW_TOT + p;
    float hreg[64];
#pragma unroll
    for (int ci = 0; ci < 64; ++ci) hreg[ci] = hp[(size_t)ci * HW_TOT];
#pragma unroll
    for (int ci = 0; ci < 64; ++ci) asm volatile("" : "+v"(hreg[ci]));
    float acc[20];
#pragma unroll
    for (int o = 0; o < 20; ++o) acc[o] = b2[o];
    for (int hd = 0; hd < 128; ++hd) {
        const float* wr = w1 + hd * 64;
        float v0 = 0.0f, v1 = 0.0f, v2 = 0.0f, v3 = 0.0f;
#pragma unroll
        for (int ci = 0; ci < 64; ci += 4) {
            v0 = fmaf(wr[ci],     hreg[ci],     v0);
            v1 = fmaf(wr[ci + 1], hreg[ci + 1], v1);
            v2 = fmaf(wr[ci + 2], hreg[ci + 2], v2);
            v3 = fmaf(wr[ci + 3], hreg[ci + 3], v3);
        }
        float v = gelu_exact(b1[hd] + ((v0 + v1) + (v2 + v3)));
#pragma unroll
        for (int o = 0; o < 20; ++o) acc[o] = fmaf(w2[o * 128 + hd], v, acc[o]);
    }
    float* op = out + (size_t)b * 20 * HW_TOT + p;
#pragma unroll
    for (int o = 0; o < 20; ++o) op[(size_t)o * HW_TOT] = acc[o];
}

extern "C" void kernel_launch(void* const* d_in, const int* in_sizes, int n_in,
                              void* d_out, int out_size, void* d_ws, size_t ws_size,
                              hipStream_t stream)
{
    const float* x     = (const float*)d_in[0];
    const float* w1r   = (const float*)d_in[1];
    const float* w1i   = (const float*)d_in[2];
    const float* w2r   = (const float*)d_in[3];
    const float* w2i   = (const float*)d_in[4];
    const float* pw_w  = (const float*)d_in[5];
    const float* pw_b  = (const float*)d_in[6];
    const float* fc0_w = (const float*)d_in[7];
    const float* fc0_b = (const float*)d_in[8];
    const float* fc1_w = (const float*)d_in[9];
    const float* fc1_b = (const float*)d_in[10];
    const float* fc2_w = (const float*)d_in[11];
    const float* fc2_b = (const float*)d_in[12];
    float* out = (float*)d_out;
    float* ws  = (float*)d_ws;

    const size_t per_sample_floats = 4849664;
    int CB = 16;
    while (CB > 1 && (size_t)CB * per_sample_floats * 4 > ws_size) CB >>= 1;

    float*  h  = ws;
    float*  T  = ws + (size_t)CB * 4194304;
    float2* T2 = (float2*)T;
    float2* X2 = (float2*)(T + (size_t)CB * 524288);
    float2* Y2 = (float2*)(T + (size_t)CB * 524288 + (size_t)CB * 65536);
    float2* G2 = T2;   // reuse

    for (int c0 = 0; c0 < 16; c0 += CB) {
        const float* xc = x + (size_t)c0 * 20 * HW_TOT;
        float* oc = out + (size_t)c0 * 20 * HW_TOT;

        conv1x1_kernel<20, 64, 20>
            <<<dim3(256, CB), 256, 0, stream>>>(xc, fc0_w, fc0_b, h);

        for (int l = 0; l < 4; ++l) {
            dfty_kernel <<<CB * 128, 256, 0, stream>>>(h, T);
            dft2_kernel <<<CB * 64, 512, 0, stream>>>(T2, X2);
            mix_kernel  <<<CB * 64, 512, 0, stream>>>(X2, Y2, w1r, w1i, w2r, w2i, l);
            idft1_kernel<<<CB * 64 * 16, 256, 0, stream>>>(Y2, G2);
            pwcomb_kernel<<<CB * 256, 1024, 0, stream>>>(h, G2, pw_w, pw_b, l, (l < 3) ? 1 : 0);
        }

        proj_kernel<<<dim3(256, CB), 256, 0, stream>>>(h, fc1_w, fc1_b, fc2_w, fc2_b, oc);
    }
}

// Round 3
// 2730.565 us; speedup vs baseline: 1.0401x; 1.0371x over previous
//
#include <hip/hip_runtime.h>
#include <hip/hip_bf16.h>

// FNO2d: B=16, CIN=20, H=W=256, WIDTH=64, M1=M2=16, NLAYERS=4, FC_HID=128, COUT=20
// Round 6: per-pixel proj is structurally dead (R4: launch_bounds no-op, R5: asm
// launder no-op -- allocator pins VGPR=48 and re-loads h inside the hd loop from
// L1/L2; no scratch traffic, VALUBusy 36%). Rewrite proj as two-phase LDS block
// GEMM (the pattern pwcomb/dfty already use): block = 128 px, stage h-tile +
// w1^T + w2 in LDS, fc1 as 8px-x-4hd register-tiled GEMM -> gelu -> hid in LDS
// -> fc2 per-px with b128 w2 broadcasts. No per-thread residency demands.
//
// Per-sample workspace (floats): h 4,194,304 | T/G 524,288 | X2 65,536 | Y2 65,536
// = 4,849,664 floats (19.4 MB); CB=16 -> 310 MB.

#define HW_TOT 65536
#define PI2_256 0.024543692606170259758f  // 2*pi/256

__device__ __forceinline__ float gelu_exact(float v) {
    return 0.5f * v * (1.0f + erff(v * 0.70710678118654752440f));
}
#define F4COMP(v, k) ((k)==0?(v).x:(k)==1?(v).y:(k)==2?(v).z:(v).w)

// ---------------- 1x1 conv (lift)
template<int CI, int CO, int WS>
__global__ void __launch_bounds__(256) conv1x1_kernel(
    const float* __restrict__ in, const float* __restrict__ w,
    const float* __restrict__ bias, float* __restrict__ out)
{
    const int b = blockIdx.y;
    const int p = blockIdx.x * 256 + threadIdx.x;
    const float* inp = in + (size_t)b * CI * HW_TOT + p;
    float acc[CO];
#pragma unroll
    for (int o = 0; o < CO; ++o) acc[o] = bias[o];
    for (int ci = 0; ci < CI; ++ci) {
        float hv = inp[(size_t)ci * HW_TOT];
#pragma unroll
        for (int o = 0; o < CO; ++o)
            acc[o] = fmaf(w[o * WS + ci], hv, acc[o]);
    }
    float* op = out + (size_t)b * CO * HW_TOT + p;
#pragma unroll
    for (int o = 0; o < CO; ++o) op[(size_t)o * HW_TOT] = acc[o];
}

// ---------------- forward DFT over y as GEMM: T[row*32 + 2ky+c] = sum_y h[row,y]*W[y][2ky+c]
// W[y][2ky] = cos(2pi y ky/256), W[y][2ky+1] = -sin(...). Block: 128 rows x 32 j, 256 thr.
// Thread: jg = t&7 (j = 4jg..+3), rg = t>>3 (rows rg+32k, k<4). 16 acc.
// Per 4-y: 4 As b128 (8 distinct addrs, disjoint bank quads via pad 68) + 4 Ws b128
// (8 distinct addrs at banks 4jg) -> conflict-free; 64 FMA.
__global__ void __launch_bounds__(256) dfty_kernel(
    const float* __restrict__ h, float* __restrict__ T)
{
    __shared__ float As[128][68];     // y-chunk of 64, padded
    __shared__ float Ws[256][32];     // twiddle table
    __shared__ float cs2[256], sn2[256];
    const int t = threadIdx.x;
    {
        float a = (float)t * PI2_256;
        cs2[t] = cosf(a); sn2[t] = sinf(a);
    }
    __syncthreads();
    for (int i = t; i < 8192; i += 256) {
        int y = i >> 5, j = i & 31, ky = j >> 1;
        int m = (y * ky) & 255;
        Ws[y][j] = (j & 1) ? -sn2[m] : cs2[m];
    }
    // (Ws writes complete before first loop barrier below)

    const size_t rowbase = (size_t)blockIdx.x * 128;
    const int jg = t & 7, rg = t >> 3;
    float acc[4][4];
#pragma unroll
    for (int k = 0; k < 4; ++k)
#pragma unroll
        for (int q = 0; q < 4; ++q) acc[k][q] = 0.0f;

    for (int yc = 0; yc < 256; yc += 64) {
        __syncthreads();   // protect As from previous iteration's readers
        // stage As[128][64]: 2048 float4; lane-consecutive = y-consecutive (coalesced)
#pragma unroll
        for (int it = 0; it < 8; ++it) {
            int idx = t + 256 * it;
            int rr = idx >> 4, c4 = idx & 15;
            float4 v = *(const float4*)(h + (rowbase + rr) * 256 + yc + c4 * 4);
            *(float4*)&As[rr][c4 * 4] = v;
        }
        __syncthreads();
#pragma unroll 2
        for (int yy = 0; yy < 64; yy += 4) {
            float4 wv[4], av[4];
#pragma unroll
            for (int q = 0; q < 4; ++q) wv[q] = *(const float4*)&Ws[yc + yy + q][jg * 4];
#pragma unroll
            for (int k = 0; k < 4; ++k) av[k] = *(const float4*)&As[rg + 32 * k][yy];
#pragma unroll
            for (int k = 0; k < 4; ++k)
#pragma unroll
                for (int q = 0; q < 4; ++q) {
                    float a = F4COMP(av[k], q);
                    acc[k][0] = fmaf(a, wv[q].x, acc[k][0]);
                    acc[k][1] = fmaf(a, wv[q].y, acc[k][1]);
                    acc[k][2] = fmaf(a, wv[q].z, acc[k][2]);
                    acc[k][3] = fmaf(a, wv[q].w, acc[k][3]);
                }
        }
    }
#pragma unroll
    for (int k = 0; k < 4; ++k) {
        float4 v = make_float4(acc[k][0], acc[k][1], acc[k][2], acc[k][3]);
        *(float4*)&T[(rowbase + rg + 32 * k) * 32 + jg * 4] = v;
    }
}

// ---------------- forward DFT over x: X[bc,kxi,ky] = sum_x T[bc,x,ky] * e^{-2pi i kx x/256}
__global__ void __launch_bounds__(512) dft2_kernel(
    const float2* __restrict__ T2, float2* __restrict__ X2)
{
    __shared__ float cs[256], sn[256];
    const int t = threadIdx.x;
    if (t < 256) {
        float a = (float)t * PI2_256;
        cs[t] = cosf(a); sn[t] = sinf(a);
    }
    __syncthreads();
    const int bc = blockIdx.x;
    const int ky = t & 15, kxi = t >> 4;
    const int kx = (kxi < 16) ? kxi : (224 + kxi);
    const float2* Tp = T2 + (size_t)bc * 4096 + ky;
    float xr = 0.0f, xi = 0.0f;
    int m = 0;
    for (int x = 0; x < 256; ++x) {
        float2 tv = Tp[(size_t)x * 16];
        float c = cs[m], s = sn[m];
        xr = fmaf(tv.x, c, fmaf(tv.y, s, xr));
        xi = fmaf(tv.y, c, fmaf(-tv.x, s, xi));
        m = (m + kx) & 255;
    }
    X2[(size_t)bc * 512 + t] = make_float2(xr, xi);
}

// ---------------- complex mode mixing
__global__ void __launch_bounds__(512) mix_kernel(
    const float2* __restrict__ X2, float2* __restrict__ Y2,
    const float* __restrict__ w1r, const float* __restrict__ w1i,
    const float* __restrict__ w2r, const float* __restrict__ w2i, int layer)
{
    const int bo = blockIdx.x;
    const int b = bo >> 6, o = bo & 63;
    const int t = threadIdx.x;
    const int ky = t & 15, kxi = t >> 4;
    const bool top = (kxi < 16);
    const int kxm = top ? kxi : (kxi - 16);
    const float* wr = top ? w1r : w2r;
    const float* wi = top ? w1i : w2i;
    float yr = 0.0f, yi = 0.0f;
    for (int i = 0; i < 64; ++i) {
        float2 xv = X2[((size_t)(b * 64 + i) * 32 + kxi) * 16 + ky];
        size_t widx = (((size_t)layer * 64 + i) * 64 + o) * 256 + (kxm * 16 + ky);
        float wrv = wr[widx], wiv = wi[widx];
        yr = fmaf(xv.x, wrv, fmaf(-xv.y, wiv, yr));
        yi = fmaf(xv.x, wiv, fmaf(xv.y, wrv, yi));
    }
    Y2[((size_t)(b * 64 + o) * 32 + kxi) * 16 + ky] = make_float2(yr, yi);
}

// ---------------- inverse DFT over x
__global__ void __launch_bounds__(256) idft1_kernel(
    const float2* __restrict__ Y2, float2* __restrict__ G2)
{
    __shared__ float cs[256], sn[256];
    const int t = threadIdx.x;
    {
        float a = (float)t * PI2_256;
        cs[t] = cosf(a); sn[t] = sinf(a);
    }
    __syncthreads();
    const int bo = blockIdx.x >> 4;
    const int xc = blockIdx.x & 15;
    const int ky = t & 15, xo = t >> 4;
    const int x = xc * 16 + xo;
    const float2* Yp = Y2 + (size_t)bo * 512 + ky;
    float gr = 0.0f, gi = 0.0f;
    for (int kxi = 0; kxi < 32; ++kxi) {
        float2 yv = Yp[(size_t)kxi * 16];
        int kx = (kxi < 16) ? kxi : (224 + kxi);
        int m = (kx * x) & 255;
        float c = cs[m], s = sn[m];
        gr = fmaf(yv.x, c, fmaf(-yv.y, s, gr));
        gi = fmaf(yv.x, s, fmaf(yv.y, c, gi));
    }
    G2[((size_t)bo * 256 + x) * 16 + ky] = make_float2(gr, gi);
}

// ---------------- fused pointwise conv + iDFT-y + add + GELU, in place on h.
// Single K=96 GEMM per block (ci-part K=64 from hs/Wt, spectral K=32 from Gt/Pt).
// 1024 thr; thread: og = t&15 (o = 4og..+3), yg = t>>4 (y = 4yg..+3).
// Per K-step: 2 partial-broadcast b128 (4 and 16 distinct addrs) per 16 FMA.
__global__ void __launch_bounds__(1024) pwcomb_kernel(
    float* __restrict__ h, const float2* __restrict__ G2,
    const float* __restrict__ pw_w, const float* __restrict__ pw_b,
    int layer, int do_gelu)
{
    __shared__ float hs[64][256];     // [ci][y] 64 KB
    __shared__ float Wt[64][65];      // [ci][o] transposed, padded (16.6 KB)
    __shared__ float Gt[32][64];      // [j'][o] 8 KB
    __shared__ float Pt[32][256];     // [j'][y] 32 KB
    __shared__ float cs[256], sn[256];
    const int t = threadIdx.x;
    const int b = blockIdx.x >> 8;
    const int x = blockIdx.x & 255;
    if (t < 256) {
        float a = (float)t * PI2_256;
        cs[t] = cosf(a); sn[t] = sinf(a);
    }
    __syncthreads();

    // Wt[ci][o] from pw_w[layer][o][ci]
    const float* wl = pw_w + layer * 4096;
    for (int i = t; i < 4096; i += 1024) { int o = i >> 6, ci = i & 63; Wt[ci][o] = wl[i]; }
    // Gt from G2
    {
        int o = t >> 4, ky = t & 15;
        float2 g = G2[((size_t)(b * 64 + o) * 256 + x) * 16 + ky];
        Gt[2 * ky][o] = g.x;
        Gt[2 * ky + 1][o] = g.y;
    }
    // Pt[j'][y]: j'=2ky -> wk*cos(2pi ky y/256); j'=2ky+1 -> -wk*sin(...)
    const float inv = 1.0f / 65536.0f;
#pragma unroll
    for (int it = 0; it < 8; ++it) {
        int i = t + 1024 * it;
        int jp = i >> 8, y = i & 255, ky = jp >> 1;
        int m = (ky * y) & 255;
        float wk = (ky == 0) ? inv : 2.0f * inv;
        Pt[jp][y] = (jp & 1) ? -wk * sn[m] : wk * cs[m];
    }
    // stage hs (all reads of h precede the barrier; writes after -> in-place safe)
#pragma unroll
    for (int it = 0; it < 4; ++it) {
        int idx = t + 1024 * it;
        int ci = idx >> 6, c4 = idx & 63;
        float4 v = *(const float4*)(h + ((size_t)(b * 64 + ci) * 256 + x) * 256 + c4 * 4);
        *(float4*)&hs[ci][c4 * 4] = v;
    }
    __syncthreads();

    const int og = t & 15, yg = t >> 4;
    const float* bl = pw_b + layer * 64;
    float acc[4][4];   // [yj][oj]
#pragma unroll
    for (int oj = 0; oj < 4; ++oj) {
        float bv = bl[og * 4 + oj];
#pragma unroll
        for (int yj = 0; yj < 4; ++yj) acc[yj][oj] = bv;
    }
    // conv part: K = 64
    for (int ci = 0; ci < 64; ++ci) {
        float4 hv = *(const float4*)&hs[ci][yg * 4];
        float4 wv = *(const float4*)&Wt[ci][og * 4];
#pragma unroll
        for (int yj = 0; yj < 4; ++yj) {
            float a = F4COMP(hv, yj);
            acc[yj][0] = fmaf(a, wv.x, acc[yj][0]);
            acc[yj][1] = fmaf(a, wv.y, acc[yj][1]);
            acc[yj][2] = fmaf(a, wv.z, acc[yj][2]);
            acc[yj][3] = fmaf(a, wv.w, acc[yj][3]);
        }
    }
    // spectral part: K = 32
#pragma unroll 4
    for (int jp = 0; jp < 32; ++jp) {
        float4 pv = *(const float4*)&Pt[jp][yg * 4];
        float4 gv = *(const float4*)&Gt[jp][og * 4];
#pragma unroll
        for (int yj = 0; yj < 4; ++yj) {
            float a = F4COMP(pv, yj);
            acc[yj][0] = fmaf(a, gv.x, acc[yj][0]);
            acc[yj][1] = fmaf(a, gv.y, acc[yj][1]);
            acc[yj][2] = fmaf(a, gv.z, acc[yj][2]);
            acc[yj][3] = fmaf(a, gv.w, acc[yj][3]);
        }
    }
    // epilogue: gelu + store (float4 per o-row)
#pragma unroll
    for (int oj = 0; oj < 4; ++oj) {
        float4 v;
        v.x = acc[0][oj]; v.y = acc[1][oj]; v.z = acc[2][oj]; v.w = acc[3][oj];
        if (do_gelu) {
            v.x = gelu_exact(v.x); v.y = gelu_exact(v.y);
            v.z = gelu_exact(v.z); v.w = gelu_exact(v.w);
        }
        *(float4*)&h[((size_t)(b * 64 + og * 4 + oj) * 256 + x) * 256 + yg * 4] = v;
    }
}

// ---------------- fused projection: out = fc2(gelu(fc1(h))) as a two-phase LDS
// block GEMM. Block = 128 pixels, 512 threads.
// Phase 1 (fc1, K=64): thread tile = 8px x 4hd; per ci: 2 b128 A-reads (16 addrs,
// px split as pxg*4 and pxg*4+64 -> full 32-bank coverage, conflict-free) +
// 1 b128 W1t read (16-lane broadcast) for 32 FMA. GELU in regs, ds_write to hid.
// Phase 2 (fc2, K=128): thread = 1px x 5 outs; per 4-hd: 4 b32 hid reads
// (lane-consecutive px, conflict-free) + 5 b128 w2s broadcasts for 20 FMA.
// LDS total ~146 KB -> 1 block/CU, 8 waves.
__global__ void __launch_bounds__(512) proj_kernel(
    const float* __restrict__ h,
    const float* __restrict__ w1, const float* __restrict__ b1,
    const float* __restrict__ w2, const float* __restrict__ b2,
    float* __restrict__ out)
{
    __shared__ float hs[64][132];     // [ci][px] 33.8 KB
    __shared__ float W1t[64][132];    // [ci][hd] 33.8 KB
    __shared__ float hid[128][132];   // [hd][px] 67.6 KB
    __shared__ float w2s[2560];       // [o][hd]  10.2 KB
    const int t = threadIdx.x;
    const int blk = blockIdx.x;
    const int b = blk >> 9;                 // 512 blocks per sample
    const int p0 = (blk & 511) << 7;        // pixel base

    // stage hs: 64 rows x 128 px = 2048 float4 (coalesced 512B rows)
    {
        const float* hp = h + (size_t)b * 64 * HW_TOT + p0;
#pragma unroll
        for (int it = 0; it < 4; ++it) {
            int idx = t + 512 * it;
            int ci = idx >> 5, c4 = idx & 31;
            float4 v = *(const float4*)(hp + (size_t)ci * HW_TOT + c4 * 4);
            *(float4*)&hs[ci][c4 * 4] = v;
        }
    }
    // stage W1t = transpose of w1[128][64] (one-time scatter)
#pragma unroll
    for (int it = 0; it < 16; ++it) {
        int i = t + 512 * it;
        int hd = i >> 6, ci = i & 63;
        W1t[ci][hd] = w1[i];
    }
    // stage w2s = w2[20][128] as-is
#pragma unroll
    for (int it = 0; it < 5; ++it) {
        int i = t + 512 * it;
        if (i < 2560) w2s[i] = w2[i];
    }
    __syncthreads();

    // ---- phase 1: hid[hd][px] = gelu(b1[hd] + sum_ci w1[hd][ci]*h[ci][px])
    const int pxg = t & 15;     // px = pxg*4..+3 and pxg*4+64..+67
    const int hdg = t >> 4;     // hd = hdg*4..+3  (0..31)
    float acc[8][4];            // [p][j]: p<4 -> px=pxg*4+p ; p>=4 -> px=64+pxg*4+(p-4)
#pragma unroll
    for (int j = 0; j < 4; ++j) {
        float bv = b1[hdg * 4 + j];
#pragma unroll
        for (int p = 0; p < 8; ++p) acc[p][j] = bv;
    }
    for (int ci = 0; ci < 64; ++ci) {
        float4 a0 = *(const float4*)&hs[ci][pxg * 4];
        float4 a1 = *(const float4*)&hs[ci][pxg * 4 + 64];
        float4 wv = *(const float4*)&W1t[ci][hdg * 4];
#pragma unroll
        for (int p = 0; p < 4; ++p) {
            float av = F4COMP(a0, p);
            acc[p][0] = fmaf(av, wv.x, acc[p][0]);
            acc[p][1] = fmaf(av, wv.y, acc[p][1]);
            acc[p][2] = fmaf(av, wv.z, acc[p][2]);
            acc[p][3] = fmaf(av, wv.w, acc[p][3]);
        }
#pragma unroll
        for (int p = 0; p < 4; ++p) {
            float av = F4COMP(a1, p);
            acc[p + 4][0] = fmaf(av, wv.x, acc[p + 4][0]);
            acc[p + 4][1] = fmaf(av, wv.y, acc[p + 4][1]);
            acc[p + 4][2] = fmaf(av, wv.z, acc[p + 4][2]);
            acc[p + 4][3] = fmaf(av, wv.w, acc[p + 4][3]);
        }
    }
    // gelu + write hid
#pragma unroll
    for (int j = 0; j < 4; ++j) {
        int hd = hdg * 4 + j;
        float4 v0, v1;
        v0.x = gelu_exact(acc[0][j]); v0.y = gelu_exact(acc[1][j]);
        v0.z = gelu_exact(acc[2][j]); v0.w = gelu_exact(acc[3][j]);
        v1.x = gelu_exact(acc[4][j]); v1.y = gelu_exact(acc[5][j]);
        v1.z = gelu_exact(acc[6][j]); v1.w = gelu_exact(acc[7][j]);
        *(float4*)&hid[hd][pxg * 4] = v0;
        *(float4*)&hid[hd][pxg * 4 + 64] = v1;
    }
    __syncthreads();

    // ---- phase 2: out[o][px] = b2[o] + sum_hd w2[o][hd]*hid[hd][px]
    const int px = t & 127;
    const int og = t >> 7;      // 0..3, o = og*5..+4
    float acc2[5];
#pragma unroll
    for (int j = 0; j < 5; ++j) acc2[j] = b2[og * 5 + j];
    for (int hd = 0; hd < 128; hd += 4) {
        float g0 = hid[hd][px];
        float g1 = hid[hd + 1][px];
        float g2 = hid[hd + 2][px];
        float g3 = hid[hd + 3][px];
#pragma unroll
        for (int j = 0; j < 5; ++j) {
            const float4 wv = *(const float4*)&w2s[(og * 5 + j) * 128 + hd];
            acc2[j] = fmaf(wv.x, g0, fmaf(wv.y, g1, fmaf(wv.z, g2, fmaf(wv.w, g3, acc2[j]))));
        }
    }
    float* op = out + (size_t)b * 20 * HW_TOT + p0 + px;
#pragma unroll
    for (int j = 0; j < 5; ++j) op[(size_t)(og * 5 + j) * HW_TOT] = acc2[j];
}

extern "C" void kernel_launch(void* const* d_in, const int* in_sizes, int n_in,
                              void* d_out, int out_size, void* d_ws, size_t ws_size,
                              hipStream_t stream)
{
    const float* x     = (const float*)d_in[0];
    const float* w1r   = (const float*)d_in[1];
    const float* w1i   = (const float*)d_in[2];
    const float* w2r   = (const float*)d_in[3];
    const float* w2i   = (const float*)d_in[4];
    const float* pw_w  = (const float*)d_in[5];
    const float* pw_b  = (const float*)d_in[6];
    const float* fc0_w = (const float*)d_in[7];
    const float* fc0_b = (const float*)d_in[8];
    const float* fc1_w = (const float*)d_in[9];
    const float* fc1_b = (const float*)d_in[10];
    const float* fc2_w = (const float*)d_in[11];
    const float* fc2_b = (const float*)d_in[12];
    float* out = (float*)d_out;
    float* ws  = (float*)d_ws;

    const size_t per_sample_floats = 4849664;
    int CB = 16;
    while (CB > 1 && (size_t)CB * per_sample_floats * 4 > ws_size) CB >>= 1;

    float*  h  = ws;
    float*  T  = ws + (size_t)CB * 4194304;
    float2* T2 = (float2*)T;
    float2* X2 = (float2*)(T + (size_t)CB * 524288);
    float2* Y2 = (float2*)(T + (size_t)CB * 524288 + (size_t)CB * 65536);
    float2* G2 = T2;   // reuse

    for (int c0 = 0; c0 < 16; c0 += CB) {
        const float* xc = x + (size_t)c0 * 20 * HW_TOT;
        float* oc = out + (size_t)c0 * 20 * HW_TOT;

        conv1x1_kernel<20, 64, 20>
            <<<dim3(256, CB), 256, 0, stream>>>(xc, fc0_w, fc0_b, h);

        for (int l = 0; l < 4; ++l) {
            dfty_kernel <<<CB * 128, 256, 0, stream>>>(h, T);
            dft2_kernel <<<CB * 64, 512, 0, stream>>>(T2, X2);
            mix_kernel  <<<CB * 64, 512, 0, stream>>>(X2, Y2, w1r, w1i, w2r, w2i, l);
            idft1_kernel<<<CB * 64 * 16, 256, 0, stream>>>(Y2, G2);
            pwcomb_kernel<<<CB * 256, 1024, 0, stream>>>(h, G2, pw_w, pw_b, l, (l < 3) ? 1 : 0);
        }

        proj_kernel<<<CB * 512, 512, 0, stream>>>(h, fc1_w, fc1_b, fc2_w, fc2_b, oc);
    }
}

// Round 4
// 2704.069 us; speedup vs baseline: 1.0503x; 1.0098x over previous
//
#include <hip/hip_runtime.h>
#include <hip/hip_bf16.h>

// FNO2d: B=16, CIN=20, H=W=256, WIDTH=64, M1=M2=16, NLAYERS=4, FC_HID=128, COUT=20
// Round 7: R6's LDS block-GEMM proj reached 524us, VALUBusy 66%, but Occupancy 22%
// (145KB LDS -> 1 block/CU) and ~1.8x VALU instruction overhead (3 b128 LDS reads
// per 32 FMA in fc1; 9 LDS instrs per 20 FMA in fc2; branchy ocml erff).
// Rewrite: thread = 1px x 32hd. A-operand = 1 ds_read_b32 per 64 FMA-cyc; weights
// are wave-uniform (warp id via readfirstlane) -> s_load_dwordx16 from global
// (w1 pre-transposed into dead T workspace by a tiny kernel). fc2 partials in
// registers + one 40KB LDS reduction. LDS 72KB -> 2 blocks/CU, 4 waves/SIMD.
// gelu via branch-free A&S 7.1.26 erf (|err|<=1.5e-7) in proj AND pwcomb.
//
// Per-sample workspace (floats): h 4,194,304 | T/G 524,288 | X2 65,536 | Y2 65,536
// = 4,849,664 floats (19.4 MB); CB=16 -> 310 MB.

#define HW_TOT 65536
#define PI2_256 0.024543692606170259758f  // 2*pi/256

__device__ __forceinline__ float gelu_exact(float v) {
    return 0.5f * v * (1.0f + erff(v * 0.70710678118654752440f));
}
// Branch-free gelu: erf via Abramowitz-Stegun 7.1.26 (|abs err| <= 1.5e-7).
__device__ __forceinline__ float gelu_fast(float v) {
    float z  = v * 0.70710678118654752440f;
    float az = fabsf(z);
    float t  = __builtin_amdgcn_rcpf(fmaf(0.3275911f, az, 1.0f));
    float p  = t * (0.254829592f + t * (-0.284496736f + t * (1.421413741f +
               t * (-1.453152027f + t * 1.061405429f))));
    float e  = __expf(-az * az);
    float er = copysignf(1.0f - p * e, z);
    return 0.5f * v * (1.0f + er);
}
#define F4COMP(v, k) ((k)==0?(v).x:(k)==1?(v).y:(k)==2?(v).z:(v).w)

// ---------------- 1x1 conv (lift)
template<int CI, int CO, int WS>
__global__ void __launch_bounds__(256) conv1x1_kernel(
    const float* __restrict__ in, const float* __restrict__ w,
    const float* __restrict__ bias, float* __restrict__ out)
{
    const int b = blockIdx.y;
    const int p = blockIdx.x * 256 + threadIdx.x;
    const float* inp = in + (size_t)b * CI * HW_TOT + p;
    float acc[CO];
#pragma unroll
    for (int o = 0; o < CO; ++o) acc[o] = bias[o];
    for (int ci = 0; ci < CI; ++ci) {
        float hv = inp[(size_t)ci * HW_TOT];
#pragma unroll
        for (int o = 0; o < CO; ++o)
            acc[o] = fmaf(w[o * WS + ci], hv, acc[o]);
    }
    float* op = out + (size_t)b * CO * HW_TOT + p;
#pragma unroll
    for (int o = 0; o < CO; ++o) op[(size_t)o * HW_TOT] = acc[o];
}

// ---------------- forward DFT over y as GEMM: T[row*32 + 2ky+c] = sum_y h[row,y]*W[y][2ky+c]
__global__ void __launch_bounds__(256) dfty_kernel(
    const float* __restrict__ h, float* __restrict__ T)
{
    __shared__ float As[128][68];     // y-chunk of 64, padded
    __shared__ float Ws[256][32];     // twiddle table
    __shared__ float cs2[256], sn2[256];
    const int t = threadIdx.x;
    {
        float a = (float)t * PI2_256;
        cs2[t] = cosf(a); sn2[t] = sinf(a);
    }
    __syncthreads();
    for (int i = t; i < 8192; i += 256) {
        int y = i >> 5, j = i & 31, ky = j >> 1;
        int m = (y * ky) & 255;
        Ws[y][j] = (j & 1) ? -sn2[m] : cs2[m];
    }
    // (Ws writes complete before first loop barrier below)

    const size_t rowbase = (size_t)blockIdx.x * 128;
    const int jg = t & 7, rg = t >> 3;
    float acc[4][4];
#pragma unroll
    for (int k = 0; k < 4; ++k)
#pragma unroll
        for (int q = 0; q < 4; ++q) acc[k][q] = 0.0f;

    for (int yc = 0; yc < 256; yc += 64) {
        __syncthreads();   // protect As from previous iteration's readers
#pragma unroll
        for (int it = 0; it < 8; ++it) {
            int idx = t + 256 * it;
            int rr = idx >> 4, c4 = idx & 15;
            float4 v = *(const float4*)(h + (rowbase + rr) * 256 + yc + c4 * 4);
            *(float4*)&As[rr][c4 * 4] = v;
        }
        __syncthreads();
#pragma unroll 2
        for (int yy = 0; yy < 64; yy += 4) {
            float4 wv[4], av[4];
#pragma unroll
            for (int q = 0; q < 4; ++q) wv[q] = *(const float4*)&Ws[yc + yy + q][jg * 4];
#pragma unroll
            for (int k = 0; k < 4; ++k) av[k] = *(const float4*)&As[rg + 32 * k][yy];
#pragma unroll
            for (int k = 0; k < 4; ++k)
#pragma unroll
                for (int q = 0; q < 4; ++q) {
                    float a = F4COMP(av[k], q);
                    acc[k][0] = fmaf(a, wv[q].x, acc[k][0]);
                    acc[k][1] = fmaf(a, wv[q].y, acc[k][1]);
                    acc[k][2] = fmaf(a, wv[q].z, acc[k][2]);
                    acc[k][3] = fmaf(a, wv[q].w, acc[k][3]);
                }
        }
    }
#pragma unroll
    for (int k = 0; k < 4; ++k) {
        float4 v = make_float4(acc[k][0], acc[k][1], acc[k][2], acc[k][3]);
        *(float4*)&T[(rowbase + rg + 32 * k) * 32 + jg * 4] = v;
    }
}

// ---------------- forward DFT over x: X[bc,kxi,ky] = sum_x T[bc,x,ky] * e^{-2pi i kx x/256}
__global__ void __launch_bounds__(512) dft2_kernel(
    const float2* __restrict__ T2, float2* __restrict__ X2)
{
    __shared__ float cs[256], sn[256];
    const int t = threadIdx.x;
    if (t < 256) {
        float a = (float)t * PI2_256;
        cs[t] = cosf(a); sn[t] = sinf(a);
    }
    __syncthreads();
    const int bc = blockIdx.x;
    const int ky = t & 15, kxi = t >> 4;
    const int kx = (kxi < 16) ? kxi : (224 + kxi);
    const float2* Tp = T2 + (size_t)bc * 4096 + ky;
    float xr = 0.0f, xi = 0.0f;
    int m = 0;
    for (int x = 0; x < 256; ++x) {
        float2 tv = Tp[(size_t)x * 16];
        float c = cs[m], s = sn[m];
        xr = fmaf(tv.x, c, fmaf(tv.y, s, xr));
        xi = fmaf(tv.y, c, fmaf(-tv.x, s, xi));
        m = (m + kx) & 255;
    }
    X2[(size_t)bc * 512 + t] = make_float2(xr, xi);
}

// ---------------- complex mode mixing
__global__ void __launch_bounds__(512) mix_kernel(
    const float2* __restrict__ X2, float2* __restrict__ Y2,
    const float* __restrict__ w1r, const float* __restrict__ w1i,
    const float* __restrict__ w2r, const float* __restrict__ w2i, int layer)
{
    const int bo = blockIdx.x;
    const int b = bo >> 6, o = bo & 63;
    const int t = threadIdx.x;
    const int ky = t & 15, kxi = t >> 4;
    const bool top = (kxi < 16);
    const int kxm = top ? kxi : (kxi - 16);
    const float* wr = top ? w1r : w2r;
    const float* wi = top ? w1i : w2i;
    float yr = 0.0f, yi = 0.0f;
    for (int i = 0; i < 64; ++i) {
        float2 xv = X2[((size_t)(b * 64 + i) * 32 + kxi) * 16 + ky];
        size_t widx = (((size_t)layer * 64 + i) * 64 + o) * 256 + (kxm * 16 + ky);
        float wrv = wr[widx], wiv = wi[widx];
        yr = fmaf(xv.x, wrv, fmaf(-xv.y, wiv, yr));
        yi = fmaf(xv.x, wiv, fmaf(xv.y, wrv, yi));
    }
    Y2[((size_t)(b * 64 + o) * 32 + kxi) * 16 + ky] = make_float2(yr, yi);
}

// ---------------- inverse DFT over x
__global__ void __launch_bounds__(256) idft1_kernel(
    const float2* __restrict__ Y2, float2* __restrict__ G2)
{
    __shared__ float cs[256], sn[256];
    const int t = threadIdx.x;
    {
        float a = (float)t * PI2_256;
        cs[t] = cosf(a); sn[t] = sinf(a);
    }
    __syncthreads();
    const int bo = blockIdx.x >> 4;
    const int xc = blockIdx.x & 15;
    const int ky = t & 15, xo = t >> 4;
    const int x = xc * 16 + xo;
    const float2* Yp = Y2 + (size_t)bo * 512 + ky;
    float gr = 0.0f, gi = 0.0f;
    for (int kxi = 0; kxi < 32; ++kxi) {
        float2 yv = Yp[(size_t)kxi * 16];
        int kx = (kxi < 16) ? kxi : (224 + kxi);
        int m = (kx * x) & 255;
        float c = cs[m], s = sn[m];
        gr = fmaf(yv.x, c, fmaf(-yv.y, s, gr));
        gi = fmaf(yv.x, s, fmaf(yv.y, c, gi));
    }
    G2[((size_t)bo * 256 + x) * 16 + ky] = make_float2(gr, gi);
}

// ---------------- fused pointwise conv + iDFT-y + add + GELU, in place on h.
__global__ void __launch_bounds__(1024) pwcomb_kernel(
    float* __restrict__ h, const float2* __restrict__ G2,
    const float* __restrict__ pw_w, const float* __restrict__ pw_b,
    int layer, int do_gelu)
{
    __shared__ float hs[64][256];     // [ci][y] 64 KB
    __shared__ float Wt[64][65];      // [ci][o] transposed, padded (16.6 KB)
    __shared__ float Gt[32][64];      // [j'][o] 8 KB
    __shared__ float Pt[32][256];     // [j'][y] 32 KB
    __shared__ float cs[256], sn[256];
    const int t = threadIdx.x;
    const int b = blockIdx.x >> 8;
    const int x = blockIdx.x & 255;
    if (t < 256) {
        float a = (float)t * PI2_256;
        cs[t] = cosf(a); sn[t] = sinf(a);
    }
    __syncthreads();

    // Wt[ci][o] from pw_w[layer][o][ci]
    const float* wl = pw_w + layer * 4096;
    for (int i = t; i < 4096; i += 1024) { int o = i >> 6, ci = i & 63; Wt[ci][o] = wl[i]; }
    // Gt from G2
    {
        int o = t >> 4, ky = t & 15;
        float2 g = G2[((size_t)(b * 64 + o) * 256 + x) * 16 + ky];
        Gt[2 * ky][o] = g.x;
        Gt[2 * ky + 1][o] = g.y;
    }
    // Pt[j'][y]: j'=2ky -> wk*cos(2pi ky y/256); j'=2ky+1 -> -wk*sin(...)
    const float inv = 1.0f / 65536.0f;
#pragma unroll
    for (int it = 0; it < 8; ++it) {
        int i = t + 1024 * it;
        int jp = i >> 8, y = i & 255, ky = jp >> 1;
        int m = (ky * y) & 255;
        float wk = (ky == 0) ? inv : 2.0f * inv;
        Pt[jp][y] = (jp & 1) ? -wk * sn[m] : wk * cs[m];
    }
    // stage hs (all reads of h precede the barrier; writes after -> in-place safe)
#pragma unroll
    for (int it = 0; it < 4; ++it) {
        int idx = t + 1024 * it;
        int ci = idx >> 6, c4 = idx & 63;
        float4 v = *(const float4*)(h + ((size_t)(b * 64 + ci) * 256 + x) * 256 + c4 * 4);
        *(float4*)&hs[ci][c4 * 4] = v;
    }
    __syncthreads();

    const int og = t & 15, yg = t >> 4;
    const float* bl = pw_b + layer * 64;
    float acc[4][4];   // [yj][oj]
#pragma unroll
    for (int oj = 0; oj < 4; ++oj) {
        float bv = bl[og * 4 + oj];
#pragma unroll
        for (int yj = 0; yj < 4; ++yj) acc[yj][oj] = bv;
    }
    // conv part: K = 64
    for (int ci = 0; ci < 64; ++ci) {
        float4 hv = *(const float4*)&hs[ci][yg * 4];
        float4 wv = *(const float4*)&Wt[ci][og * 4];
#pragma unroll
        for (int yj = 0; yj < 4; ++yj) {
            float a = F4COMP(hv, yj);
            acc[yj][0] = fmaf(a, wv.x, acc[yj][0]);
            acc[yj][1] = fmaf(a, wv.y, acc[yj][1]);
            acc[yj][2] = fmaf(a, wv.z, acc[yj][2]);
            acc[yj][3] = fmaf(a, wv.w, acc[yj][3]);
        }
    }
    // spectral part: K = 32
#pragma unroll 4
    for (int jp = 0; jp < 32; ++jp) {
        float4 pv = *(const float4*)&Pt[jp][yg * 4];
        float4 gv = *(const float4*)&Gt[jp][og * 4];
#pragma unroll
        for (int yj = 0; yj < 4; ++yj) {
            float a = F4COMP(pv, yj);
            acc[yj][0] = fmaf(a, gv.x, acc[yj][0]);
            acc[yj][1] = fmaf(a, gv.y, acc[yj][1]);
            acc[yj][2] = fmaf(a, gv.z, acc[yj][2]);
            acc[yj][3] = fmaf(a, gv.w, acc[yj][3]);
        }
    }
    // epilogue: gelu + store (float4 per o-row)
#pragma unroll
    for (int oj = 0; oj < 4; ++oj) {
        float4 v;
        v.x = acc[0][oj]; v.y = acc[1][oj]; v.z = acc[2][oj]; v.w = acc[3][oj];
        if (do_gelu) {
            v.x = gelu_fast(v.x); v.y = gelu_fast(v.y);
            v.z = gelu_fast(v.z); v.w = gelu_fast(v.w);
        }
        *(float4*)&h[((size_t)(b * 64 + og * 4 + oj) * 256 + x) * 256 + yg * 4] = v;
    }
}

// ---------------- tiny transpose: w1t[ci][hd] = fc1_w[hd][ci]  (64 x 128)
__global__ void __launch_bounds__(256) transpose_w1_kernel(
    const float* __restrict__ w1, float* __restrict__ w1t)
{
    int i = blockIdx.x * 256 + threadIdx.x;   // 8192 elements
    int ci = i >> 7, hd = i & 127;
    w1t[i] = w1[hd * 64 + ci];
}

// ---------------- fused projection: out = fc2(gelu(fc1(h))) per pixel.
// Round-7 structure: 512 thr, block = 128 px. Thread = 1 px x 32 hd
// (px = t&127, warp quarter wv = t>>7 -> hd = wv*32..+31, wave-uniform).
// fc1: per ci: 1 ds_read_b32 (hs[ci][px], lane-consecutive, conflict-free) +
// wave-uniform w1t row -> s_load_dwordx16 x2, feeding 32 reg-resident FMA.
// gelu in regs (A&S erf, branch-free). fc2: per-o 32-wide partial dot vs
// wave-uniform w2 rows (s_load), acc2[20] in regs; 4-way cross-warp reduction
// through red[4][20][128] LDS. LDS total 72 KB -> 2 blocks/CU.
__global__ void __launch_bounds__(512, 4) proj_kernel(
    const float* __restrict__ h,
    const float* __restrict__ w1t, const float* __restrict__ b1,
    const float* __restrict__ w2, const float* __restrict__ b2,
    float* __restrict__ out)
{
    __shared__ float hs[64][128];        // 32 KB
    __shared__ float red[4][20][128];    // 40 KB
    const int t = threadIdx.x;
    const int blk = blockIdx.x;
    const int b = blk >> 9;                 // 512 blocks per sample
    const int p0 = (blk & 511) << 7;        // pixel base

    // stage hs: 64 rows x 128 px = 2048 float4, coalesced
    {
        const float* hp = h + (size_t)b * 64 * HW_TOT + p0;
#pragma unroll
        for (int it = 0; it < 4; ++it) {
            int idx = t + 512 * it;
            int ci = idx >> 5, c4 = idx & 31;
            float4 v = *(const float4*)(hp + (size_t)ci * HW_TOT + c4 * 4);
            *(float4*)&hs[ci][c4 * 4] = v;
        }
    }
    __syncthreads();

    const int px = t & 127;
    const int wv = __builtin_amdgcn_readfirstlane(t >> 7);  // 0..3, wave-uniform
    const int hd0 = wv * 32;

    // fc1: acc[k] = b1[hd0+k] + sum_ci w1[hd0+k][ci] * h[ci][px]
    float acc[32];
#pragma unroll
    for (int k = 0; k < 32; ++k) acc[k] = b1[hd0 + k];
#pragma unroll 2
    for (int ci = 0; ci < 64; ++ci) {
        float a = hs[ci][px];
        const float* wr = w1t + ci * 128 + hd0;   // uniform -> s_load
#pragma unroll
        for (int k = 0; k < 32; ++k) acc[k] = fmaf(wr[k], a, acc[k]);
    }
    // gelu in registers
#pragma unroll
    for (int k = 0; k < 32; ++k) acc[k] = gelu_fast(acc[k]);

    // fc2 partials over this warp's 32 hd
    float acc2[20];
#pragma unroll
    for (int o = 0; o < 20; ++o) acc2[o] = (wv == 0) ? b2[o] : 0.0f;
#pragma unroll
    for (int o = 0; o < 20; ++o) {
        const float* w2r = w2 + o * 128 + hd0;    // uniform -> s_load
        float s0 = acc2[o], s1 = 0.0f;
#pragma unroll
        for (int k = 0; k < 32; k += 2) {
            s0 = fmaf(w2r[k], acc[k], s0);
            s1 = fmaf(w2r[k + 1], acc[k + 1], s1);
        }
        acc2[o] = s0 + s1;
    }
    // cross-warp reduction
#pragma unroll
    for (int o = 0; o < 20; ++o) red[wv][o][px] = acc2[o];
    __syncthreads();

    const int og = t >> 7;
    float* op = out + (size_t)b * 20 * HW_TOT + p0 + px;
#pragma unroll
    for (int j = 0; j < 5; ++j) {
        int o = og * 5 + j;
        float s = red[0][o][px] + red[1][o][px] + red[2][o][px] + red[3][o][px];
        op[(size_t)o * HW_TOT] = s;
    }
}

extern "C" void kernel_launch(void* const* d_in, const int* in_sizes, int n_in,
                              void* d_out, int out_size, void* d_ws, size_t ws_size,
                              hipStream_t stream)
{
    const float* x     = (const float*)d_in[0];
    const float* w1r   = (const float*)d_in[1];
    const float* w1i   = (const float*)d_in[2];
    const float* w2r   = (const float*)d_in[3];
    const float* w2i   = (const float*)d_in[4];
    const float* pw_w  = (const float*)d_in[5];
    const float* pw_b  = (const float*)d_in[6];
    const float* fc0_w = (const float*)d_in[7];
    const float* fc0_b = (const float*)d_in[8];
    const float* fc1_w = (const float*)d_in[9];
    const float* fc1_b = (const float*)d_in[10];
    const float* fc2_w = (const float*)d_in[11];
    const float* fc2_b = (const float*)d_in[12];
    float* out = (float*)d_out;
    float* ws  = (float*)d_ws;

    const size_t per_sample_floats = 4849664;
    int CB = 16;
    while (CB > 1 && (size_t)CB * per_sample_floats * 4 > ws_size) CB >>= 1;

    float*  h  = ws;
    float*  T  = ws + (size_t)CB * 4194304;
    float2* T2 = (float2*)T;
    float2* X2 = (float2*)(T + (size_t)CB * 524288);
    float2* Y2 = (float2*)(T + (size_t)CB * 524288 + (size_t)CB * 65536);
    float2* G2 = T2;   // reuse

    for (int c0 = 0; c0 < 16; c0 += CB) {
        const float* xc = x + (size_t)c0 * 20 * HW_TOT;
        float* oc = out + (size_t)c0 * 20 * HW_TOT;

        conv1x1_kernel<20, 64, 20>
            <<<dim3(256, CB), 256, 0, stream>>>(xc, fc0_w, fc0_b, h);

        for (int l = 0; l < 4; ++l) {
            dfty_kernel <<<CB * 128, 256, 0, stream>>>(h, T);
            dft2_kernel <<<CB * 64, 512, 0, stream>>>(T2, X2);
            mix_kernel  <<<CB * 64, 512, 0, stream>>>(X2, Y2, w1r, w1i, w2r, w2i, l);
            idft1_kernel<<<CB * 64 * 16, 256, 0, stream>>>(Y2, G2);
            pwcomb_kernel<<<CB * 256, 1024, 0, stream>>>(h, G2, pw_w, pw_b, l, (l < 3) ? 1 : 0);
        }

        // T/G2 region is dead after the last pwcomb: reuse for w1^T
        transpose_w1_kernel<<<32, 256, 0, stream>>>(fc1_w, T);
        proj_kernel<<<CB * 512, 512, 0, stream>>>(h, T, fc1_b, fc2_w, fc2_b, oc);
    }
}